// Round 12
// baseline (294.375 us; speedup 1.0000x reference)
//
#include <hip/hip_runtime.h>
#include <hip/hip_bf16.h>

// Problem constants
#define NE 384      // n_embed
#define HD 64       // head dim
#define TT 8        // block (sequence) length
#define NBATCH 32768

typedef __bf16 bf16;
typedef bf16 bf16x8 __attribute__((ext_vector_type(8)));
typedef bf16 bf16x4 __attribute__((ext_vector_type(4)));
typedef float f32x4 __attribute__((ext_vector_type(4)));

// async global->LDS, 16B per lane, dest = wave-uniform LDS base + lane*16
#define GLOAD_LDS16(g, l) __builtin_amdgcn_global_load_lds(                    \
    (const __attribute__((address_space(1))) void*)(g),                        \
    (__attribute__((address_space(3))) void*)(l), 16, 0, 0)

// ---------------------------------------------------------------------------
// Kernel 0: convert Wq|Wk|Wv (each [384,64] f32, row-major, y = x@W) into a
// bf16 fragment table in MFMA B-fragment order:
//   wt[((kk*12 + n)*64 + lane)*8 + j] = W_all[kk*32 + (lane>>4)*8 + j][col]
//   col = n*16 + (lane&15)
// ---------------------------------------------------------------------------
__global__ void prep_wt(const float* __restrict__ Wq, const float* __restrict__ Wk,
                        const float* __restrict__ Wv, bf16* __restrict__ wt) {
    int c = blockIdx.x * blockDim.x + threadIdx.x;
    if (c >= 12 * 12 * 64) return;
    int kk   = c / (12 * 64);
    int rem  = c % (12 * 64);
    int n    = rem / 64;
    int lane = rem % 64;
    int col  = n * 16 + (lane & 15);
    const float* src; int cc;
    if (col < 64)       { src = Wq; cc = col; }
    else if (col < 128) { src = Wk; cc = col - 64; }
    else                { src = Wv; cc = col - 128; }
    int k0 = kk * 32 + (lane >> 4) * 8;
    bf16* dst = wt + (size_t)c * 8;
    #pragma unroll
    for (int j = 0; j < 8; ++j)
        dst[j] = (bf16)src[(size_t)(k0 + j) * 64 + cc];
}

// ---------------------------------------------------------------------------
// DIAGNOSTIC build of the round-3 kernel (124.8 µs structure, unchanged):
// the whole body repeats NREP times; reps 0..NREP-2 write to `junk`
// (workspace), the last rep writes `out`. Identical deterministic work per
// rep. Purpose: push dur_us above the harness fill kernels (~230 µs) so the
// fused kernel finally appears in the rocprof top-5 and we read its
// FETCH/WRITE/MfmaUtil/VALUBusy/Occupancy/LDS-conflict counters.
// ---------------------------------------------------------------------------
template<bool PREP, int NREP>
__global__ __launch_bounds__(256, 3)
void fused_head(const float* __restrict__ x, const bf16* __restrict__ wt,
                const float* __restrict__ Wq, const float* __restrict__ Wk,
                const float* __restrict__ Wv, float* __restrict__ out,
                float* __restrict__ junk) {
    constexpr int STQ = 72;  // q2/k2 row stride (elems)
    constexpr int STV = 40;  // vT/wei row stride (elems)
    constexpr int WSZ = 2 * 16 * STQ + 64 * STV + 16 * STV;  // 5504 elems/wave
    constexpr int BBUF = 12 * 512;                           // 12 KB / K-step
    __shared__ __align__(16) bf16 smem[4 * WSZ];             // 44032 B/block

    const int tid  = threadIdx.x;
    const int wid  = tid >> 6;
    const int lane = tid & 63;
    const int lr   = lane & 15;
    const int lg   = lane >> 4;

    bf16* q2  = smem + wid * WSZ;
    bf16* k2  = q2 + 16 * STQ;
    bf16* vT  = k2 + 16 * STQ;
    bf16* wei = vT + 64 * STV;

    const int wg   = blockIdx.x * 4 + wid;
    const int row0 = wg * 32;

    const float qk_scale = 0.051031036307982884f;  // 384^-0.5
    const f32x4 zero4 = {0.f, 0.f, 0.f, 0.f};

    #pragma unroll 1
    for (int rep = 0; rep < NREP; ++rep) {
        float* dst = (rep == NREP - 1) ? out : junk;

        f32x4 acc[2][12];
        #pragma unroll
        for (int m = 0; m < 2; ++m)
            #pragma unroll
            for (int n = 0; n < 12; ++n) acc[m][n] = zero4;

        const float* xb0 = x + (size_t)(row0 + lr) * NE + lg * 8;
        const float* xb1 = xb0 + (size_t)16 * NE;

        f32x4 c0lo = *(const f32x4*)(xb0);
        f32x4 c0hi = *(const f32x4*)(xb0 + 4);
        f32x4 c1lo = *(const f32x4*)(xb1);
        f32x4 c1hi = *(const f32x4*)(xb1 + 4);

        if (PREP) {
            // prologue: stage K-step 0 into buffer 0 (3 fragments per wave)
            #pragma unroll
            for (int i = 0; i < 3; ++i) {
                int n = wid * 3 + i;
                GLOAD_LDS16(wt + ((size_t)(0 * 12 + n) * 64 + lane) * 8,
                            smem + n * 512);
            }
            __syncthreads();

            for (int kk = 0; kk < 12; ++kk) {
                const int cur = kk & 1;
                if (kk < 11) {
                    #pragma unroll
                    for (int i = 0; i < 3; ++i) {
                        int n = wid * 3 + i;
                        GLOAD_LDS16(wt + ((size_t)((kk + 1) * 12 + n) * 64 + lane) * 8,
                                    smem + (cur ^ 1) * BBUF + n * 512);
                    }
                }

                bf16x8 a0, a1;
                #pragma unroll
                for (int j = 0; j < 4; ++j) {
                    a0[j]     = (bf16)c0lo[j];
                    a0[j + 4] = (bf16)c0hi[j];
                    a1[j]     = (bf16)c1lo[j];
                    a1[j + 4] = (bf16)c1hi[j];
                }

                if (kk < 11) {
                    const float* p0 = xb0 + (kk + 1) * 32;
                    const float* p1 = xb1 + (kk + 1) * 32;
                    c0lo = *(const f32x4*)(p0);
                    c0hi = *(const f32x4*)(p0 + 4);
                    c1lo = *(const f32x4*)(p1);
                    c1hi = *(const f32x4*)(p1 + 4);
                }

                const bf16* bb = smem + cur * BBUF;
                #pragma unroll
                for (int n = 0; n < 12; ++n) {
                    bf16x8 b = *(const bf16x8*)(bb + n * 512 + lane * 8);
                    acc[0][n] = __builtin_amdgcn_mfma_f32_16x16x32_bf16(a0, b, acc[0][n], 0, 0, 0);
                    acc[1][n] = __builtin_amdgcn_mfma_f32_16x16x32_bf16(a1, b, acc[1][n], 0, 0, 0);
                }
                __syncthreads();
            }
        } else {
            for (int kk = 0; kk < 12; ++kk) {
                bf16x8 a0, a1;
                #pragma unroll
                for (int j = 0; j < 4; ++j) {
                    a0[j]     = (bf16)c0lo[j];
                    a0[j + 4] = (bf16)c0hi[j];
                    a1[j]     = (bf16)c1lo[j];
                    a1[j + 4] = (bf16)c1hi[j];
                }
                if (kk < 11) {
                    const float* p0 = xb0 + (kk + 1) * 32;
                    const float* p1 = xb1 + (kk + 1) * 32;
                    c0lo = *(const f32x4*)(p0);
                    c0hi = *(const f32x4*)(p0 + 4);
                    c1lo = *(const f32x4*)(p1);
                    c1hi = *(const f32x4*)(p1 + 4);
                }
                #pragma unroll
                for (int n = 0; n < 12; ++n) {
                    int col = n * 16 + lr;
                    const float* ws = (col < 64) ? (Wq + col)
                                     : (col < 128) ? (Wk + (col - 64))
                                                   : (Wv + (col - 128));
                    bf16x8 b;
                    #pragma unroll
                    for (int j = 0; j < 8; ++j)
                        b[j] = (bf16)ws[(size_t)(kk * 32 + lg * 8 + j) * 64];
                    acc[0][n] = __builtin_amdgcn_mfma_f32_16x16x32_bf16(a0, b, acc[0][n], 0, 0, 0);
                    acc[1][n] = __builtin_amdgcn_mfma_f32_16x16x32_bf16(a1, b, acc[1][n], 0, 0, 0);
                }
            }
        }

        // zero the K=32 padding regions (cols 16..31)
        {
            unsigned int* z = (unsigned int*)(vT + lane * STV + 16);
            #pragma unroll
            for (int j = 0; j < 8; ++j) z[j] = 0u;
            if (lane < 16) {
                unsigned int* zw = (unsigned int*)(wei + lane * STV + 16);
                #pragma unroll
                for (int j = 0; j < 8; ++j) zw[j] = 0u;
            }
        }

        #pragma unroll
        for (int p = 0; p < 2; ++p) {
            #pragma unroll
            for (int nt = 0; nt < 4; ++nt) {
                #pragma unroll
                for (int r = 0; r < 4; ++r) {
                    q2[(4 * lg + r) * STQ + nt * 16 + lr] = (bf16)acc[p][nt][r];
                    k2[(4 * lg + r) * STQ + nt * 16 + lr] = (bf16)acc[p][4 + nt][r];
                }
                bf16x4 vv;
                vv[0] = (bf16)acc[p][8 + nt][0];
                vv[1] = (bf16)acc[p][8 + nt][1];
                vv[2] = (bf16)acc[p][8 + nt][2];
                vv[3] = (bf16)acc[p][8 + nt][3];
                *(bf16x4*)(vT + (nt * 16 + lr) * STV + lg * 4) = vv;
            }

            f32x4 w4 = zero4;
            #pragma unroll
            for (int kh = 0; kh < 2; ++kh) {
                bf16x8 qa = *(const bf16x8*)(q2 + lr * STQ + kh * 32 + lg * 8);
                bf16x8 kb = *(const bf16x8*)(k2 + lr * STQ + kh * 32 + lg * 8);
                w4 = __builtin_amdgcn_mfma_f32_16x16x32_bf16(qa, kb, w4, 0, 0, 0);
            }

            const int sb = lr >> 3;
            const int s  = lr & 7;
            #pragma unroll
            for (int r = 0; r < 4; ++r) {
                int tp = 4 * lg + r;
                bool valid = ((tp >> 3) == sb) && (s <= (tp & 7));
                float val = valid ? w4[r] * qk_scale : -1e30f;
                float mx = val;
                mx = fmaxf(mx, __shfl_xor(mx, 1));
                mx = fmaxf(mx, __shfl_xor(mx, 2));
                mx = fmaxf(mx, __shfl_xor(mx, 4));
                float e = valid ? __expf(val - mx) : 0.f;
                float sm = e;
                sm += __shfl_xor(sm, 1);
                sm += __shfl_xor(sm, 2);
                sm += __shfl_xor(sm, 4);
                float pn = valid ? e / sm : 0.f;
                wei[tp * STV + lr] = (bf16)pn;
            }

            bf16x8 pa = *(const bf16x8*)(wei + lr * STV + lg * 8);
            const int bb2 = wg * 4 + p * 2;
            #pragma unroll
            for (int nt = 0; nt < 4; ++nt) {
                bf16x8 vb = *(const bf16x8*)(vT + (nt * 16 + lr) * STV + lg * 8);
                f32x4 o = __builtin_amdgcn_mfma_f32_16x16x32_bf16(pa, vb, zero4, 0, 0, 0);
                #pragma unroll
                for (int r = 0; r < 4; ++r) {
                    int tp = 4 * lg + r;
                    dst[((size_t)(bb2 + (tp >> 3)) * TT + (tp & 7)) * HD + nt * 16 + lr] = o[r];
                }
            }
        }

        // protect per-wave scratch from next rep's block-shared staging
        __syncthreads();
    }
}

// ---------------------------------------------------------------------------
extern "C" void kernel_launch(void* const* d_in, const int* in_sizes, int n_in,
                              void* d_out, int out_size, void* d_ws, size_t ws_size,
                              hipStream_t stream) {
    const float* x  = (const float*)d_in[0];
    const float* Wq = (const float*)d_in[1];
    const float* Wk = (const float*)d_in[2];
    const float* Wv = (const float*)d_in[3];
    float* out = (float*)d_out;

    const size_t wt_bytes   = (size_t)12 * 12 * 64 * 8 * sizeof(bf16);   // 147456
    const size_t junk_need  = (size_t)(1 << 20) + (size_t)out_size * 4;  // 1MB + out
    const int grid = NBATCH / 16;   // 2048 blocks, 4 waves x 4 batches each

    if (ws_size >= wt_bytes) {
        bf16* wt = (bf16*)d_ws;
        prep_wt<<<36, 256, 0, stream>>>(Wq, Wk, Wv, wt);
        if (ws_size >= junk_need + wt_bytes) {
            float* junk = (float*)((char*)d_ws + (1 << 20));
            fused_head<true, 3><<<grid, 256, 0, stream>>>(x, wt, nullptr, nullptr, nullptr, out, junk);
        } else {
            fused_head<true, 1><<<grid, 256, 0, stream>>>(x, wt, nullptr, nullptr, nullptr, out, out);
        }
    } else {
        fused_head<false, 1><<<grid, 256, 0, stream>>>(x, nullptr, Wq, Wk, Wv, out, out);
    }
}